// Round 9
// baseline (81.258 us; speedup 1.0000x reference)
//
#include <hip/hip_runtime.h>

#define NPOINTS 500000
#define RESOLUTION 128.0f
#define IDX_SIZE 524288u     // INDEX_TABLE_SIZE (2^19)
#define IDX_MASK 0x7FFFFu
#define FEAT_MASK 0xFFFFFu   // FEATURE_TABLE_SIZE-1 (2^20)
#define P1 2654435761u
#define P2 805459861u

typedef float    f4v __attribute__((ext_vector_type(4)));
typedef unsigned u2v __attribute__((ext_vector_type(2)));
typedef unsigned u4v __attribute__((ext_vector_type(4)));

constexpr unsigned mulinv32(unsigned a) {
    unsigned x = 1u;
    for (int i = 0; i < 6; ++i) x *= 2u - a * x;
    return x;
}
constexpr unsigned P2INV = mulinv32(P2);
static_assert(((P2INV * P2) & FEAT_MASK) == 1u, "bad inverse");

__device__ inline unsigned bf16pack(float a, float b) {
    unsigned ua = __float_as_uint(a); ua = (ua + 0x7FFFu + ((ua >> 16) & 1u)) >> 16;
    unsigned ub = __float_as_uint(b); ub = (ub + 0x7FFFu + ((ub >> 16) & 1u)) >> 16;
    return ua | (ub << 16);
}
__device__ inline float bf16lo(unsigned u) { return __uint_as_float(u << 16); }
__device__ inline float bf16hi(unsigned u) { return __uint_as_float(u & 0xFFFF0000u); }

// ---------------- Phase 0: feature_table f32[2^20][4] -> bf16x4[2^20] (8B rows).
// Pure coalesced stream: 16MB read + 8MB write. Halves phase-1 stream bytes.
__global__ __launch_bounds__(256) void pack_ft16(
    const f4v* __restrict__ ftp,
    u2v* __restrict__ ft16)
{
    unsigned i = blockIdx.x * blockDim.x + threadIdx.x;   // grid exact: 2^20
    f4v v = ftp[i];
    u2v o;
    o.x = bf16pack(v.x, v.y);
    o.y = bf16pack(v.z, v.w);
    ft16[i] = o;
}

// ---------------- Phase 1 (y-order): 8 XOR-offset line-perfect bf16 feature
// streams (64MB total) + random 32B index gather + scattered 8B F store.
__global__ __launch_bounds__(256) void build_F_y16(
    const u2v* __restrict__ ft16,
    const float* __restrict__ index_table,
    u2v* __restrict__ F)
{
    unsigned y = blockIdx.x * blockDim.x + threadIdx.x;   // 0..2^20-1
    unsigned h = (y * P2INV) & FEAT_MASK;                 // h*P2 mod 2^20 == y
    if (h >= IDX_SIZE) return;

    // random 32B index gather first (longest latency)
    const f4v* p = (const f4v*)(index_table + (size_t)h * 8u);
    f4v iw0 = p[0];
    f4v iw1 = p[1];

    u2v fv[8];
#pragma unroll
    for (unsigned j = 0; j < 8; ++j) {
        unsigned cj = (j * P1) & FEAT_MASK;
        fv[j] = ft16[y ^ cj];
    }

    float e[8] = { iw0.x, iw0.y, iw0.z, iw0.w, iw1.x, iw1.y, iw1.z, iw1.w };
    float mx = fmaxf(fmaxf(fmaxf(e[0], e[1]), fmaxf(e[2], e[3])),
                     fmaxf(fmaxf(e[4], e[5]), fmaxf(e[6], e[7])));
    float s = 0.f;
#pragma unroll
    for (int j = 0; j < 8; ++j) { e[j] = __expf(e[j] - mx); s += e[j]; }

    float ax = 0.f, ay = 0.f, az = 0.f, aw = 0.f;
#pragma unroll
    for (int j = 0; j < 8; ++j) {
        ax = fmaf(bf16lo(fv[j].x), e[j], ax);
        ay = fmaf(bf16hi(fv[j].x), e[j], ay);
        az = fmaf(bf16lo(fv[j].y), e[j], az);
        aw = fmaf(bf16hi(fv[j].y), e[j], aw);
    }
    float inv = 1.0f / s;
    u2v packed;
    packed.x = bf16pack(ax * inv, ay * inv);
    packed.y = bf16pack(az * inv, aw * inv);
    F[h] = packed;
}

// ---------------- Phase 1 variant without ft16 (R6-proven) for mid-tier ws.
__global__ __launch_bounds__(256) void build_F_y(
    const f4v* __restrict__ ftp,
    const float* __restrict__ index_table,
    u2v* __restrict__ F)
{
    unsigned y = blockIdx.x * blockDim.x + threadIdx.x;
    unsigned h = (y * P2INV) & FEAT_MASK;
    if (h >= IDX_SIZE) return;

    const f4v* p = (const f4v*)(index_table + (size_t)h * 8u);
    f4v iw0 = p[0];
    f4v iw1 = p[1];

    f4v fv[8];
#pragma unroll
    for (unsigned j = 0; j < 8; ++j) {
        unsigned cj = (j * P1) & FEAT_MASK;
        fv[j] = ftp[y ^ cj];
    }

    float e[8] = { iw0.x, iw0.y, iw0.z, iw0.w, iw1.x, iw1.y, iw1.z, iw1.w };
    float mx = fmaxf(fmaxf(fmaxf(e[0], e[1]), fmaxf(e[2], e[3])),
                     fmaxf(fmaxf(e[4], e[5]), fmaxf(e[6], e[7])));
    float s = 0.f;
#pragma unroll
    for (int j = 0; j < 8; ++j) { e[j] = __expf(e[j] - mx); s += e[j]; }

    float ax = 0.f, ay = 0.f, az = 0.f, aw = 0.f;
#pragma unroll
    for (int j = 0; j < 8; ++j) {
        ax = fmaf(fv[j].x, e[j], ax);
        ay = fmaf(fv[j].y, e[j], ay);
        az = fmaf(fv[j].z, e[j], az);
        aw = fmaf(fv[j].w, e[j], aw);
    }
    float inv = 1.0f / s;
    u2v packed;
    packed.x = bf16pack(ax * inv, ay * inv);
    packed.y = bf16pack(az * inv, aw * inv);
    F[h] = packed;
}

// ---------------- Phase 2: two points per lane; NT on the random F-gathers
// (they can't hit 32KB L1 anyway -> skip L1 allocation work).
__global__ __launch_bounds__(256) void interp2(
    const float* __restrict__ x,
    const u2v* __restrict__ F,
    f4v* __restrict__ out)
{
    int t = blockIdx.x * blockDim.x + threadIdx.x;
    int p0 = t << 1;
    if (p0 >= NPOINTS) return;        // NPOINTS even: p0 and p0+1 both valid

    unsigned hs[16];
    float    ws[16];
#pragma unroll
    for (int r = 0; r < 2; ++r) {
        int p = p0 + r;
        float xs0 = x[p * 3 + 0] * RESOLUTION;
        float xs1 = x[p * 3 + 1] * RESOLUTION;
        float xs2 = x[p * 3 + 2] * RESOLUTION;
        int i0 = (int)xs0, i1 = (int)xs1, i2 = (int)xs2;
        float f0 = xs0 - (float)i0, f1 = xs1 - (float)i1, f2 = xs2 - (float)i2;
        float g0 = 1.0f - f0, g1 = 1.0f - f1, g2 = 1.0f - f2;
        unsigned u0 = (unsigned)i0;
        unsigned m1a = (unsigned)i1 * P1, m1b = ((unsigned)i1 + 1u) * P1;
        unsigned m2a = (unsigned)i2 * P2, m2b = ((unsigned)i2 + 1u) * P2;
#pragma unroll
        for (int c = 0; c < 8; ++c) {
            unsigned b0 = c & 1, b1 = (c >> 1) & 1, b2 = (c >> 2) & 1;
            hs[r * 8 + c] = ((u0 + b0) ^ (b1 ? m1b : m1a) ^ (b2 ? m2b : m2a)) & IDX_MASK;
            ws[r * 8 + c] = (b0 ? f0 : g0) * (b1 ? f1 : g1) * (b2 ? f2 : g2);
        }
    }

    u2v fv[16];
#pragma unroll
    for (int k = 0; k < 16; ++k) fv[k] = __builtin_nontemporal_load(F + hs[k]);

#pragma unroll
    for (int r = 0; r < 2; ++r) {
        float ax = 0.f, ay = 0.f, az = 0.f, aw = 0.f;
#pragma unroll
        for (int c = 0; c < 8; ++c) {
            int k = r * 8 + c;
            ax = fmaf(bf16lo(fv[k].x), ws[k], ax);
            ay = fmaf(bf16hi(fv[k].x), ws[k], ay);
            az = fmaf(bf16lo(fv[k].y), ws[k], az);
            aw = fmaf(bf16hi(fv[k].y), ws[k], aw);
        }
        f4v o = { ax, ay, az, aw };
        out[p0 + r] = o;
    }
}

// ---------------- Fallback (proven R1 kernel) if ws is too small ----------------
__global__ __launch_bounds__(256) void hashgrid_fwd(
    const float* __restrict__ x,
    const float* __restrict__ feature_table,
    const float* __restrict__ index_table,
    float* __restrict__ out)
{
    int tid = blockIdx.x * blockDim.x + threadIdx.x;
    int p = tid >> 3;
    int corner = tid & 7;
    if (p >= NPOINTS) return;

    float xs0 = x[p * 3 + 0] * RESOLUTION;
    float xs1 = x[p * 3 + 1] * RESOLUTION;
    float xs2 = x[p * 3 + 2] * RESOLUTION;
    int i0 = (int)xs0, i1 = (int)xs1, i2 = (int)xs2;
    float f0 = xs0 - (float)i0, f1 = xs1 - (float)i1, f2 = xs2 - (float)i2;

    unsigned b0 = corner & 1u, b1 = (corner >> 1) & 1u, b2 = (corner >> 2) & 1u;
    float w0 = b0 ? f0 : 1.0f - f0;
    float w1 = b1 ? f1 : 1.0f - f1;
    float w2 = b2 ? f2 : 1.0f - f2;
    float w = w0 * w1 * w2;

    unsigned h = (((unsigned)i0 + b0) ^ (((unsigned)i1 + b1) * P1)
                  ^ (((unsigned)i2 + b2) * P2)) & IDX_MASK;

    const float4* itp = (const float4*)(index_table + (size_t)h * 8u);
    float4 iw0 = itp[0];
    float4 iw1 = itp[1];
    float e0 = iw0.x, e1 = iw0.y, e2 = iw0.z, e3 = iw0.w;
    float e4 = iw1.x, e5 = iw1.y, e6 = iw1.z, e7 = iw1.w;

    float mx = fmaxf(fmaxf(fmaxf(e0, e1), fmaxf(e2, e3)),
                     fmaxf(fmaxf(e4, e5), fmaxf(e6, e7)));
    e0 = __expf(e0 - mx); e1 = __expf(e1 - mx);
    e2 = __expf(e2 - mx); e3 = __expf(e3 - mx);
    e4 = __expf(e4 - mx); e5 = __expf(e5 - mx);
    e6 = __expf(e6 - mx); e7 = __expf(e7 - mx);
    float s = ((e0 + e1) + (e2 + e3)) + ((e4 + e5) + (e6 + e7));

    unsigned hp2 = h * P2;
    const float4* ftp = (const float4*)feature_table;
    float ax = 0.f, ay = 0.f, az = 0.f, aw = 0.f;
    float ej[8] = {e0, e1, e2, e3, e4, e5, e6, e7};
#pragma unroll
    for (unsigned j = 0; j < 8; ++j) {
        unsigned a = ((j * P1) ^ hp2) & FEAT_MASK;
        float4 ft = ftp[a];
        ax = fmaf(ft.x, ej[j], ax);
        ay = fmaf(ft.y, ej[j], ay);
        az = fmaf(ft.z, ej[j], az);
        aw = fmaf(ft.w, ej[j], aw);
    }

    float scale = w / s;
    ax *= scale; ay *= scale; az *= scale; aw *= scale;

#pragma unroll
    for (int m = 1; m < 8; m <<= 1) {
        ax += __shfl_xor(ax, m);
        ay += __shfl_xor(ay, m);
        az += __shfl_xor(az, m);
        aw += __shfl_xor(aw, m);
    }
    if (corner == 0) {
        ((float4*)out)[p] = make_float4(ax, ay, az, aw);
    }
}

extern "C" void kernel_launch(void* const* d_in, const int* in_sizes, int n_in,
                              void* d_out, int out_size, void* d_ws, size_t ws_size,
                              hipStream_t stream) {
    const float* x  = (const float*)d_in[0];
    const float* ft = (const float*)d_in[1];
    const float* it = (const float*)d_in[2];

    const size_t F_BYTES    = (size_t)IDX_SIZE * 8u;        // 4 MiB
    const size_t FT16_BYTES = (size_t)(1u << 20) * 8u;      // 8 MiB

    if (ws_size >= F_BYTES + FT16_BYTES) {
        u2v* F    = (u2v*)d_ws;
        u2v* ft16 = (u2v*)((char*)d_ws + F_BYTES);
        hipLaunchKernelGGL(pack_ft16, dim3((1u << 20) / 256), dim3(256), 0, stream,
                           (const f4v*)ft, ft16);
        hipLaunchKernelGGL(build_F_y16, dim3((1u << 20) / 256), dim3(256), 0, stream,
                           ft16, it, F);
        const int lanes2 = NPOINTS / 2;
        hipLaunchKernelGGL(interp2, dim3((lanes2 + 255) / 256), dim3(256), 0, stream,
                           x, F, (f4v*)d_out);
    } else if (ws_size >= F_BYTES) {
        u2v* F = (u2v*)d_ws;
        hipLaunchKernelGGL(build_F_y, dim3((1u << 20) / 256), dim3(256), 0, stream,
                           (const f4v*)ft, it, F);
        const int lanes2 = NPOINTS / 2;
        hipLaunchKernelGGL(interp2, dim3((lanes2 + 255) / 256), dim3(256), 0, stream,
                           x, F, (f4v*)d_out);
    } else {
        const int total = NPOINTS * 8;
        hipLaunchKernelGGL(hashgrid_fwd, dim3((total + 255) / 256), dim3(256), 0, stream,
                           x, ft, it, (float*)d_out);
    }
}

// Round 10
// 56.627 us; speedup vs baseline: 1.4350x; 1.4350x over previous
//
#include <hip/hip_runtime.h>

#define NPOINTS 500000
#define RESOLUTION 128.0f
#define IDX_SIZE 524288u     // INDEX_TABLE_SIZE (2^19)
#define IDX_MASK 0x7FFFFu
#define FEAT_MASK 0xFFFFFu   // FEATURE_TABLE_SIZE-1 (2^20)
#define P1 2654435761u
#define P2 805459861u

typedef float    f4v __attribute__((ext_vector_type(4)));
typedef unsigned u2v __attribute__((ext_vector_type(2)));
typedef unsigned u4v __attribute__((ext_vector_type(4)));

constexpr unsigned mulinv32(unsigned a) {
    unsigned x = 1u;
    for (int i = 0; i < 6; ++i) x *= 2u - a * x;
    return x;
}
constexpr unsigned P2INV = mulinv32(P2);
static_assert(((P2INV * P2) & FEAT_MASK) == 1u, "bad inverse");

__device__ inline unsigned bf16pack(float a, float b) {
    unsigned ua = __float_as_uint(a); ua = (ua + 0x7FFFu + ((ua >> 16) & 1u)) >> 16;
    unsigned ub = __float_as_uint(b); ub = (ub + 0x7FFFu + ((ub >> 16) & 1u)) >> 16;
    return ua | (ub << 16);
}
__device__ inline float bf16lo(unsigned u) { return __uint_as_float(u << 16); }
__device__ inline float bf16hi(unsigned u) { return __uint_as_float(u & 0xFFFF0000u); }

// ---------------- Phase 1 (y-order, R6-proven): 8 XOR-offset line-perfect f32
// feature streams + random 32B index gather + scattered 8B F store. Plain
// cached accesses throughout (NT proven harmful R7/R9).
__global__ __launch_bounds__(256) void build_F_y(
    const f4v* __restrict__ ftp,
    const float* __restrict__ index_table,
    u2v* __restrict__ F)
{
    unsigned y = blockIdx.x * blockDim.x + threadIdx.x;   // 0..2^20-1
    unsigned h = (y * P2INV) & FEAT_MASK;                 // h*P2 mod 2^20 == y
    if (h >= IDX_SIZE) return;

    // random 32B index gather first (longest latency)
    const f4v* p = (const f4v*)(index_table + (size_t)h * 8u);
    f4v iw0 = p[0];
    f4v iw1 = p[1];

    f4v fv[8];
#pragma unroll
    for (unsigned j = 0; j < 8; ++j) {
        unsigned cj = (j * P1) & FEAT_MASK;
        fv[j] = ftp[y ^ cj];
    }

    float e[8] = { iw0.x, iw0.y, iw0.z, iw0.w, iw1.x, iw1.y, iw1.z, iw1.w };
    float mx = fmaxf(fmaxf(fmaxf(e[0], e[1]), fmaxf(e[2], e[3])),
                     fmaxf(fmaxf(e[4], e[5]), fmaxf(e[6], e[7])));
    float s = 0.f;
#pragma unroll
    for (int j = 0; j < 8; ++j) { e[j] = __expf(e[j] - mx); s += e[j]; }

    float ax = 0.f, ay = 0.f, az = 0.f, aw = 0.f;
#pragma unroll
    for (int j = 0; j < 8; ++j) {
        ax = fmaf(fv[j].x, e[j], ax);
        ay = fmaf(fv[j].y, e[j], ay);
        az = fmaf(fv[j].z, e[j], az);
        aw = fmaf(fv[j].w, e[j], aw);
    }
    float inv = 1.0f / s;
    u2v packed;
    packed.x = bf16pack(ax * inv, ay * inv);
    packed.y = bf16pack(az * inv, aw * inv);
    F[h] = packed;
}

// ---------------- Phase 2: two points per lane. Corner-pair trick: corners
// (b0=0,1) of a group hash to h and (i0 even) h^1 — adjacent 8B rows in one
// aligned 16B slot -> one 16B load serves both. Avg 6 L2 requests/point vs 8.
__global__ __launch_bounds__(256) void interp_pair(
    const float* __restrict__ x,
    const u2v* __restrict__ F,
    f4v* __restrict__ out)
{
    const u4v* F2 = (const u4v*)F;    // 16B rows = pairs {2k, 2k+1}

    int t = blockIdx.x * blockDim.x + threadIdx.x;
    int p0 = t << 1;
    if (p0 >= NPOINTS) return;        // NPOINTS even

#pragma unroll
    for (int r = 0; r < 2; ++r) {
        int p = p0 + r;
        float xs0 = x[p * 3 + 0] * RESOLUTION;
        float xs1 = x[p * 3 + 1] * RESOLUTION;
        float xs2 = x[p * 3 + 2] * RESOLUTION;
        int i0 = (int)xs0, i1 = (int)xs1, i2 = (int)xs2;
        float f0 = xs0 - (float)i0, f1 = xs1 - (float)i1, f2 = xs2 - (float)i2;
        float g0 = 1.0f - f0, g1 = 1.0f - f1, g2 = 1.0f - f2;

        unsigned u0 = (unsigned)i0;
        bool even0 = (u0 & 1u) == 0u;
        unsigned m1a = (unsigned)i1 * P1, m1b = ((unsigned)i1 + 1u) * P1;
        unsigned m2a = (unsigned)i2 * P2, m2b = ((unsigned)i2 + 1u) * P2;

        unsigned A0[4], A1[4];
        float    wg[4];
#pragma unroll
        for (int g = 0; g < 4; ++g) {
            unsigned b1 = g & 1, b2 = (g >> 1) & 1;
            unsigned m = (b1 ? m1b : m1a) ^ (b2 ? m2b : m2a);
            A0[g] = (u0 ^ m) & IDX_MASK;
            A1[g] = ((u0 + 1u) ^ m) & IDX_MASK;
            wg[g] = (b1 ? f1 : g1) * (b2 ? f2 : g2);
        }

        // 4 × 16B loads (cover A0's row + its 16B-slot partner)
        u4v q[4];
#pragma unroll
        for (int g = 0; g < 4; ++g) q[g] = F2[A0[g] >> 1];

        // odd-i0: partner row is elsewhere -> 4 predicated 8B loads
        u2v rb[4];
        if (!even0) {
#pragma unroll
            for (int g = 0; g < 4; ++g) rb[g] = F[A1[g]];
        }

        float ax = 0.f, ay = 0.f, az = 0.f, aw = 0.f;
#pragma unroll
        for (int g = 0; g < 4; ++g) {
            u2v lo = { q[g].x, q[g].y };
            u2v hi = { q[g].z, q[g].w };
            bool a0hi = (A0[g] & 1u) != 0u;
            u2v r0 = a0hi ? hi : lo;                       // row A0[g]
            u2v r1 = even0 ? (a0hi ? lo : hi) : rb[g];     // row A1[g]
            float w0 = g0 * wg[g], w1 = f0 * wg[g];
            ax = fmaf(bf16lo(r0.x), w0, ax);
            ay = fmaf(bf16hi(r0.x), w0, ay);
            az = fmaf(bf16lo(r0.y), w0, az);
            aw = fmaf(bf16hi(r0.y), w0, aw);
            ax = fmaf(bf16lo(r1.x), w1, ax);
            ay = fmaf(bf16hi(r1.x), w1, ay);
            az = fmaf(bf16lo(r1.y), w1, az);
            aw = fmaf(bf16hi(r1.y), w1, aw);
        }
        f4v o = { ax, ay, az, aw };
        out[p] = o;
    }
}

// ---------------- Fallback (proven R1 kernel) if ws is too small ----------------
__global__ __launch_bounds__(256) void hashgrid_fwd(
    const float* __restrict__ x,
    const float* __restrict__ feature_table,
    const float* __restrict__ index_table,
    float* __restrict__ out)
{
    int tid = blockIdx.x * blockDim.x + threadIdx.x;
    int p = tid >> 3;
    int corner = tid & 7;
    if (p >= NPOINTS) return;

    float xs0 = x[p * 3 + 0] * RESOLUTION;
    float xs1 = x[p * 3 + 1] * RESOLUTION;
    float xs2 = x[p * 3 + 2] * RESOLUTION;
    int i0 = (int)xs0, i1 = (int)xs1, i2 = (int)xs2;
    float f0 = xs0 - (float)i0, f1 = xs1 - (float)i1, f2 = xs2 - (float)i2;

    unsigned b0 = corner & 1u, b1 = (corner >> 1) & 1u, b2 = (corner >> 2) & 1u;
    float w0 = b0 ? f0 : 1.0f - f0;
    float w1 = b1 ? f1 : 1.0f - f1;
    float w2 = b2 ? f2 : 1.0f - f2;
    float w = w0 * w1 * w2;

    unsigned h = (((unsigned)i0 + b0) ^ (((unsigned)i1 + b1) * P1)
                  ^ (((unsigned)i2 + b2) * P2)) & IDX_MASK;

    const float4* itp = (const float4*)(index_table + (size_t)h * 8u);
    float4 iw0 = itp[0];
    float4 iw1 = itp[1];
    float e0 = iw0.x, e1 = iw0.y, e2 = iw0.z, e3 = iw0.w;
    float e4 = iw1.x, e5 = iw1.y, e6 = iw1.z, e7 = iw1.w;

    float mx = fmaxf(fmaxf(fmaxf(e0, e1), fmaxf(e2, e3)),
                     fmaxf(fmaxf(e4, e5), fmaxf(e6, e7)));
    e0 = __expf(e0 - mx); e1 = __expf(e1 - mx);
    e2 = __expf(e2 - mx); e3 = __expf(e3 - mx);
    e4 = __expf(e4 - mx); e5 = __expf(e5 - mx);
    e6 = __expf(e6 - mx); e7 = __expf(e7 - mx);
    float s = ((e0 + e1) + (e2 + e3)) + ((e4 + e5) + (e6 + e7));

    unsigned hp2 = h * P2;
    const float4* ftp = (const float4*)feature_table;
    float ax = 0.f, ay = 0.f, az = 0.f, aw = 0.f;
    float ej[8] = {e0, e1, e2, e3, e4, e5, e6, e7};
#pragma unroll
    for (unsigned j = 0; j < 8; ++j) {
        unsigned a = ((j * P1) ^ hp2) & FEAT_MASK;
        float4 ft = ftp[a];
        ax = fmaf(ft.x, ej[j], ax);
        ay = fmaf(ft.y, ej[j], ay);
        az = fmaf(ft.z, ej[j], az);
        aw = fmaf(ft.w, ej[j], aw);
    }

    float scale = w / s;
    ax *= scale; ay *= scale; az *= scale; aw *= scale;

#pragma unroll
    for (int m = 1; m < 8; m <<= 1) {
        ax += __shfl_xor(ax, m);
        ay += __shfl_xor(ay, m);
        az += __shfl_xor(az, m);
        aw += __shfl_xor(aw, m);
    }
    if (corner == 0) {
        ((float4*)out)[p] = make_float4(ax, ay, az, aw);
    }
}

extern "C" void kernel_launch(void* const* d_in, const int* in_sizes, int n_in,
                              void* d_out, int out_size, void* d_ws, size_t ws_size,
                              hipStream_t stream) {
    const float* x  = (const float*)d_in[0];
    const float* ft = (const float*)d_in[1];
    const float* it = (const float*)d_in[2];

    const size_t F_BYTES = (size_t)IDX_SIZE * 8u;   // 4 MiB (bf16x4 rows)

    if (ws_size >= F_BYTES) {
        u2v* F = (u2v*)d_ws;
        hipLaunchKernelGGL(build_F_y, dim3((1u << 20) / 256), dim3(256), 0, stream,
                           (const f4v*)ft, it, F);
        const int lanes2 = NPOINTS / 2;
        hipLaunchKernelGGL(interp_pair, dim3((lanes2 + 255) / 256), dim3(256), 0, stream,
                           x, F, (f4v*)d_out);
    } else {
        const int total = NPOINTS * 8;
        hipLaunchKernelGGL(hashgrid_fwd, dim3((total + 255) / 256), dim3(256), 0, stream,
                           x, ft, it, (float*)d_out);
    }
}

// Round 11
// 51.995 us; speedup vs baseline: 1.5628x; 1.0891x over previous
//
#include <hip/hip_runtime.h>

#define NPOINTS 500000
#define RESOLUTION 128.0f
#define IDX_SIZE 524288u     // INDEX_TABLE_SIZE (2^19)
#define IDX_MASK 0x7FFFFu
#define FEAT_MASK 0xFFFFFu   // FEATURE_TABLE_SIZE-1 (2^20)
#define P1 2654435761u
#define P2 805459861u

typedef float    f4v __attribute__((ext_vector_type(4)));
typedef unsigned u2v __attribute__((ext_vector_type(2)));
typedef unsigned u4v __attribute__((ext_vector_type(4)));

constexpr unsigned mulinv32(unsigned a) {
    unsigned x = 1u;
    for (int i = 0; i < 6; ++i) x *= 2u - a * x;
    return x;
}
constexpr unsigned P2INV = mulinv32(P2);
static_assert(((P2INV * P2) & FEAT_MASK) == 1u, "bad inverse");

__device__ inline unsigned bf16pack(float a, float b) {
    unsigned ua = __float_as_uint(a); ua = (ua + 0x7FFFu + ((ua >> 16) & 1u)) >> 16;
    unsigned ub = __float_as_uint(b); ub = (ub + 0x7FFFu + ((ub >> 16) & 1u)) >> 16;
    return ua | (ub << 16);
}
__device__ inline float bf16lo(unsigned u) { return __uint_as_float(u << 16); }
__device__ inline float bf16hi(unsigned u) { return __uint_as_float(u & 0xFFFF0000u); }

// ---------------- Phase 0: ft f32[2^20][4] -> bf16x4, split across two 4MiB
// halves (ws spare + d_out-as-scratch). Pure coalesced stream (16MB r, 8MB w).
__global__ __launch_bounds__(256) void pack_ft16_split(
    const f4v* __restrict__ ftp,
    u2v* __restrict__ lo,     // y < 2^19
    u2v* __restrict__ hi)     // y >= 2^19
{
    unsigned i = blockIdx.x * blockDim.x + threadIdx.x;   // grid exact: 2^20
    f4v v = ftp[i];
    u2v o;
    o.x = bf16pack(v.x, v.y);
    o.y = bf16pack(v.z, v.w);
    if (i < (1u << 19)) lo[i] = o;
    else                hi[i - (1u << 19)] = o;
}

// ---------------- Phase 1 (y-order): 8 XOR-offset line-perfect bf16 feature
// streams (64MB total) + random 32B index gather + scattered 8B F store.
__global__ __launch_bounds__(256) void build_F_y16s(
    const u2v* __restrict__ lo,
    const u2v* __restrict__ hi,
    const float* __restrict__ index_table,
    u2v* __restrict__ F)
{
    unsigned y = blockIdx.x * blockDim.x + threadIdx.x;   // 0..2^20-1
    unsigned h = (y * P2INV) & FEAT_MASK;                 // h*P2 mod 2^20 == y
    if (h >= IDX_SIZE) return;

    // random 32B index gather first (longest latency)
    const f4v* p = (const f4v*)(index_table + (size_t)h * 8u);
    f4v iw0 = p[0];
    f4v iw1 = p[1];

    u2v fv[8];
#pragma unroll
    for (unsigned j = 0; j < 8; ++j) {
        unsigned idx = y ^ ((j * P1) & FEAT_MASK);
        fv[j] = (idx >> 19) ? hi[idx & 0x7FFFFu] : lo[idx];
    }

    float e[8] = { iw0.x, iw0.y, iw0.z, iw0.w, iw1.x, iw1.y, iw1.z, iw1.w };
    float mx = fmaxf(fmaxf(fmaxf(e[0], e[1]), fmaxf(e[2], e[3])),
                     fmaxf(fmaxf(e[4], e[5]), fmaxf(e[6], e[7])));
    float s = 0.f;
#pragma unroll
    for (int j = 0; j < 8; ++j) { e[j] = __expf(e[j] - mx); s += e[j]; }

    float ax = 0.f, ay = 0.f, az = 0.f, aw = 0.f;
#pragma unroll
    for (int j = 0; j < 8; ++j) {
        ax = fmaf(bf16lo(fv[j].x), e[j], ax);
        ay = fmaf(bf16hi(fv[j].x), e[j], ay);
        az = fmaf(bf16lo(fv[j].y), e[j], az);
        aw = fmaf(bf16hi(fv[j].y), e[j], aw);
    }
    float inv = 1.0f / s;
    u2v packed;
    packed.x = bf16pack(ax * inv, ay * inv);
    packed.y = bf16pack(az * inv, aw * inv);
    F[h] = packed;
}

// ---------------- Phase 1 fallback without ft16 (R6-proven) for small ws.
__global__ __launch_bounds__(256) void build_F_y(
    const f4v* __restrict__ ftp,
    const float* __restrict__ index_table,
    u2v* __restrict__ F)
{
    unsigned y = blockIdx.x * blockDim.x + threadIdx.x;
    unsigned h = (y * P2INV) & FEAT_MASK;
    if (h >= IDX_SIZE) return;

    const f4v* p = (const f4v*)(index_table + (size_t)h * 8u);
    f4v iw0 = p[0];
    f4v iw1 = p[1];

    f4v fv[8];
#pragma unroll
    for (unsigned j = 0; j < 8; ++j) {
        unsigned cj = (j * P1) & FEAT_MASK;
        fv[j] = ftp[y ^ cj];
    }

    float e[8] = { iw0.x, iw0.y, iw0.z, iw0.w, iw1.x, iw1.y, iw1.z, iw1.w };
    float mx = fmaxf(fmaxf(fmaxf(e[0], e[1]), fmaxf(e[2], e[3])),
                     fmaxf(fmaxf(e[4], e[5]), fmaxf(e[6], e[7])));
    float s = 0.f;
#pragma unroll
    for (int j = 0; j < 8; ++j) { e[j] = __expf(e[j] - mx); s += e[j]; }

    float ax = 0.f, ay = 0.f, az = 0.f, aw = 0.f;
#pragma unroll
    for (int j = 0; j < 8; ++j) {
        ax = fmaf(fv[j].x, e[j], ax);
        ay = fmaf(fv[j].y, e[j], ay);
        az = fmaf(fv[j].z, e[j], az);
        aw = fmaf(fv[j].w, e[j], aw);
    }
    float inv = 1.0f / s;
    u2v packed;
    packed.x = bf16pack(ax * inv, ay * inv);
    packed.y = bf16pack(az * inv, aw * inv);
    F[h] = packed;
}

// ---------------- Phase 2 (R10-proven): corner-pair 16B loads.
__global__ __launch_bounds__(256) void interp_pair(
    const float* __restrict__ x,
    const u2v* __restrict__ F,
    f4v* __restrict__ out)
{
    const u4v* F2 = (const u4v*)F;    // 16B rows = pairs {2k, 2k+1}

    int t = blockIdx.x * blockDim.x + threadIdx.x;
    int p0 = t << 1;
    if (p0 >= NPOINTS) return;        // NPOINTS even

#pragma unroll
    for (int r = 0; r < 2; ++r) {
        int p = p0 + r;
        float xs0 = x[p * 3 + 0] * RESOLUTION;
        float xs1 = x[p * 3 + 1] * RESOLUTION;
        float xs2 = x[p * 3 + 2] * RESOLUTION;
        int i0 = (int)xs0, i1 = (int)xs1, i2 = (int)xs2;
        float f0 = xs0 - (float)i0, f1 = xs1 - (float)i1, f2 = xs2 - (float)i2;
        float g0 = 1.0f - f0, g1 = 1.0f - f1, g2 = 1.0f - f2;

        unsigned u0 = (unsigned)i0;
        bool even0 = (u0 & 1u) == 0u;
        unsigned m1a = (unsigned)i1 * P1, m1b = ((unsigned)i1 + 1u) * P1;
        unsigned m2a = (unsigned)i2 * P2, m2b = ((unsigned)i2 + 1u) * P2;

        unsigned A0[4], A1[4];
        float    wg[4];
#pragma unroll
        for (int g = 0; g < 4; ++g) {
            unsigned b1 = g & 1, b2 = (g >> 1) & 1;
            unsigned m = (b1 ? m1b : m1a) ^ (b2 ? m2b : m2a);
            A0[g] = (u0 ^ m) & IDX_MASK;
            A1[g] = ((u0 + 1u) ^ m) & IDX_MASK;
            wg[g] = (b1 ? f1 : g1) * (b2 ? f2 : g2);
        }

        u4v q[4];
#pragma unroll
        for (int g = 0; g < 4; ++g) q[g] = F2[A0[g] >> 1];

        u2v rb[4];
        if (!even0) {
#pragma unroll
            for (int g = 0; g < 4; ++g) rb[g] = F[A1[g]];
        }

        float ax = 0.f, ay = 0.f, az = 0.f, aw = 0.f;
#pragma unroll
        for (int g = 0; g < 4; ++g) {
            u2v lo = { q[g].x, q[g].y };
            u2v hi = { q[g].z, q[g].w };
            bool a0hi = (A0[g] & 1u) != 0u;
            u2v r0 = a0hi ? hi : lo;
            u2v r1 = even0 ? (a0hi ? lo : hi) : rb[g];
            float w0 = g0 * wg[g], w1 = f0 * wg[g];
            ax = fmaf(bf16lo(r0.x), w0, ax);
            ay = fmaf(bf16hi(r0.x), w0, ay);
            az = fmaf(bf16lo(r0.y), w0, az);
            aw = fmaf(bf16hi(r0.y), w0, aw);
            ax = fmaf(bf16lo(r1.x), w1, ax);
            ay = fmaf(bf16hi(r1.x), w1, ay);
            az = fmaf(bf16lo(r1.y), w1, az);
            aw = fmaf(bf16hi(r1.y), w1, aw);
        }
        f4v o = { ax, ay, az, aw };
        out[p] = o;
    }
}

// ---------------- Fallback (proven R1 kernel) if ws is too small ----------------
__global__ __launch_bounds__(256) void hashgrid_fwd(
    const float* __restrict__ x,
    const float* __restrict__ feature_table,
    const float* __restrict__ index_table,
    float* __restrict__ out)
{
    int tid = blockIdx.x * blockDim.x + threadIdx.x;
    int p = tid >> 3;
    int corner = tid & 7;
    if (p >= NPOINTS) return;

    float xs0 = x[p * 3 + 0] * RESOLUTION;
    float xs1 = x[p * 3 + 1] * RESOLUTION;
    float xs2 = x[p * 3 + 2] * RESOLUTION;
    int i0 = (int)xs0, i1 = (int)xs1, i2 = (int)xs2;
    float f0 = xs0 - (float)i0, f1 = xs1 - (float)i1, f2 = xs2 - (float)i2;

    unsigned b0 = corner & 1u, b1 = (corner >> 1) & 1u, b2 = (corner >> 2) & 1u;
    float w0 = b0 ? f0 : 1.0f - f0;
    float w1 = b1 ? f1 : 1.0f - f1;
    float w2 = b2 ? f2 : 1.0f - f2;
    float w = w0 * w1 * w2;

    unsigned h = (((unsigned)i0 + b0) ^ (((unsigned)i1 + b1) * P1)
                  ^ (((unsigned)i2 + b2) * P2)) & IDX_MASK;

    const float4* itp = (const float4*)(index_table + (size_t)h * 8u);
    float4 iw0 = itp[0];
    float4 iw1 = itp[1];
    float e0 = iw0.x, e1 = iw0.y, e2 = iw0.z, e3 = iw0.w;
    float e4 = iw1.x, e5 = iw1.y, e6 = iw1.z, e7 = iw1.w;

    float mx = fmaxf(fmaxf(fmaxf(e0, e1), fmaxf(e2, e3)),
                     fmaxf(fmaxf(e4, e5), fmaxf(e6, e7)));
    e0 = __expf(e0 - mx); e1 = __expf(e1 - mx);
    e2 = __expf(e2 - mx); e3 = __expf(e3 - mx);
    e4 = __expf(e4 - mx); e5 = __expf(e5 - mx);
    e6 = __expf(e6 - mx); e7 = __expf(e7 - mx);
    float s = ((e0 + e1) + (e2 + e3)) + ((e4 + e5) + (e6 + e7));

    unsigned hp2 = h * P2;
    const float4* ftp = (const float4*)feature_table;
    float ax = 0.f, ay = 0.f, az = 0.f, aw = 0.f;
    float ej[8] = {e0, e1, e2, e3, e4, e5, e6, e7};
#pragma unroll
    for (unsigned j = 0; j < 8; ++j) {
        unsigned a = ((j * P1) ^ hp2) & FEAT_MASK;
        float4 ft = ftp[a];
        ax = fmaf(ft.x, ej[j], ax);
        ay = fmaf(ft.y, ej[j], ay);
        az = fmaf(ft.z, ej[j], az);
        aw = fmaf(ft.w, ej[j], aw);
    }

    float scale = w / s;
    ax *= scale; ay *= scale; az *= scale; aw *= scale;

#pragma unroll
    for (int m = 1; m < 8; m <<= 1) {
        ax += __shfl_xor(ax, m);
        ay += __shfl_xor(ay, m);
        az += __shfl_xor(az, m);
        aw += __shfl_xor(aw, m);
    }
    if (corner == 0) {
        ((float4*)out)[p] = make_float4(ax, ay, az, aw);
    }
}

extern "C" void kernel_launch(void* const* d_in, const int* in_sizes, int n_in,
                              void* d_out, int out_size, void* d_ws, size_t ws_size,
                              hipStream_t stream) {
    const float* x  = (const float*)d_in[0];
    const float* ft = (const float*)d_in[1];
    const float* it = (const float*)d_in[2];

    const size_t F_BYTES    = (size_t)IDX_SIZE * 8u;        // 4 MiB
    const size_t HALF_BYTES = (size_t)(1u << 19) * 8u;      // 4 MiB per ft16 half
    const size_t OUT_BYTES  = (size_t)out_size * 4u;        // 8e6 B

    if (ws_size >= F_BYTES + HALF_BYTES && OUT_BYTES >= HALF_BYTES) {
        u2v* F       = (u2v*)d_ws;
        u2v* ft16_lo = (u2v*)((char*)d_ws + F_BYTES);
        u2v* ft16_hi = (u2v*)d_out;    // d_out as scratch; overwritten by interp last
        hipLaunchKernelGGL(pack_ft16_split, dim3((1u << 20) / 256), dim3(256), 0, stream,
                           (const f4v*)ft, ft16_lo, ft16_hi);
        hipLaunchKernelGGL(build_F_y16s, dim3((1u << 20) / 256), dim3(256), 0, stream,
                           ft16_lo, ft16_hi, it, F);
        const int lanes2 = NPOINTS / 2;
        hipLaunchKernelGGL(interp_pair, dim3((lanes2 + 255) / 256), dim3(256), 0, stream,
                           x, F, (f4v*)d_out);
    } else if (ws_size >= F_BYTES) {
        u2v* F = (u2v*)d_ws;
        hipLaunchKernelGGL(build_F_y, dim3((1u << 20) / 256), dim3(256), 0, stream,
                           (const f4v*)ft, it, F);
        const int lanes2 = NPOINTS / 2;
        hipLaunchKernelGGL(interp_pair, dim3((lanes2 + 255) / 256), dim3(256), 0, stream,
                           x, F, (f4v*)d_out);
    } else {
        const int total = NPOINTS * 8;
        hipLaunchKernelGGL(hashgrid_fwd, dim3((total + 255) / 256), dim3(256), 0, stream,
                           x, ft, it, (float*)d_out);
    }
}